// Round 5
// baseline (452.814 us; speedup 1.0000x reference)
//
#include <hip/hip_runtime.h>

#define B_   2
#define S_   2048
#define D_   2048
#define H_   16
#define HD_  128
#define WIN_ 256
#define M_   (B_ * S_)  // 4096

typedef float  f32x4  __attribute__((ext_vector_type(4)));
typedef short  s16x8  __attribute__((ext_vector_type(8)));
typedef __bf16 bf16x8 __attribute__((ext_vector_type(8)));
typedef unsigned short ushort_t;

__device__ inline unsigned short f2b(float f) {
  unsigned u = __builtin_bit_cast(unsigned, f);
  u += 0x7fffu + ((u >> 16) & 1u);  // RNE
  return (unsigned short)(u >> 16);
}
__device__ inline float b2f(unsigned short h) {
  unsigned u = ((unsigned)h) << 16;
  return __builtin_bit_cast(float, u);
}

// Hedged MFMA call: gfx950 builtin may take v8bf16 (upstream clang) or v8i16.
template <typename T>
__device__ auto mfma_impl(T a, T b, f32x4 c, int)
    -> decltype(__builtin_amdgcn_mfma_f32_16x16x32_bf16(a, b, c, 0, 0, 0)) {
  return __builtin_amdgcn_mfma_f32_16x16x32_bf16(a, b, c, 0, 0, 0);
}
template <typename T>
__device__ f32x4 mfma_impl(T a, T b, f32x4 c, long) {
  return __builtin_amdgcn_mfma_f32_16x16x32_bf16(
      __builtin_bit_cast(bf16x8, a), __builtin_bit_cast(bf16x8, b), c, 0, 0, 0);
}
__device__ inline f32x4 mfma_bf16(s16x8 a, s16x8 b, f32x4 c) {
  return mfma_impl(a, b, c, 0);
}

// ---- async global->LDS, 16B/lane. lds base must be wave-uniform; lane i lands at +i*16B.
#if defined(__has_builtin)
#if __has_builtin(__builtin_amdgcn_global_load_lds)
#define HAS_GLL 1
#endif
#endif
#ifndef HAS_GLL
#define HAS_GLL 0
#endif

__device__ inline void gl_lds16(const ushort_t* g, ushort_t* lds_wave_base) {
#if HAS_GLL
  __builtin_amdgcn_global_load_lds(
      (const __attribute__((address_space(1))) unsigned int*)g,
      (__attribute__((address_space(3))) unsigned int*)lds_wave_base, 16, 0, 0);
#else
  const int lane = threadIdx.x & 63;
  *(uint4*)(lds_wave_base + lane * 8) = *(const uint4*)g;
#endif
}

// ---------------- split f32 -> bf16 hi + lo ----------------
__global__ __launch_bounds__(256) void k_split(const float* __restrict__ x,
                                               ushort_t* __restrict__ hi,
                                               ushort_t* __restrict__ lo, int n) {
  int i = (blockIdx.x * 256 + threadIdx.x) * 4;
  if (i + 3 < n) {
    float4 v = *(const float4*)(x + i);
    ushort4 h, l;
    h.x = f2b(v.x); l.x = f2b(v.x - b2f(h.x));
    h.y = f2b(v.y); l.y = f2b(v.y - b2f(h.y));
    h.z = f2b(v.z); l.z = f2b(v.z - b2f(h.z));
    h.w = f2b(v.w); l.w = f2b(v.w - b2f(h.w));
    *(ushort4*)(hi + i) = h;
    *(ushort4*)(lo + i) = l;
  }
}

// ---------------- fused transpose + split of all 4 weights: z picks W ----------------
__global__ __launch_bounds__(256) void k_transpose4(const float* __restrict__ W0,
                                                    const float* __restrict__ W1,
                                                    const float* __restrict__ W2,
                                                    const float* __restrict__ W3,
                                                    ushort_t* __restrict__ T0h,
                                                    ushort_t* __restrict__ T0l,
                                                    ushort_t* __restrict__ T1h,
                                                    ushort_t* __restrict__ T1l,
                                                    ushort_t* __restrict__ T2h,
                                                    ushort_t* __restrict__ T3h) {
  __shared__ float t[32][33];
  const int z = blockIdx.z;
  const float* W = (z == 0) ? W0 : (z == 1) ? W1 : (z == 2) ? W2 : W3;
  ushort_t* Th = (z == 0) ? T0h : (z == 1) ? T1h : (z == 2) ? T2h : T3h;
  ushort_t* Tl = (z == 0) ? T0l : (z == 1) ? T1l : nullptr;
  int bx = blockIdx.x * 32, by = blockIdx.y * 32;
  int tx = threadIdx.x, ty = threadIdx.y;  // 32 x 8
#pragma unroll
  for (int r = 0; r < 32; r += 8)
    t[ty + r][tx] = W[(size_t)(by + ty + r) * D_ + bx + tx];
  __syncthreads();
#pragma unroll
  for (int r = 0; r < 32; r += 8) {
    float v = t[tx][ty + r];
    unsigned short h = f2b(v);
    Th[(size_t)(bx + ty + r) * D_ + by + tx] = h;
    if (Tl) Tl[(size_t)(bx + ty + r) * D_ + by + tx] = f2b(v - b2f(h));
  }
}

// ---------------- bf16 transpose for V: Vt[b*D + c][s] = Vb[b*S + s][c] ----------------
__global__ __launch_bounds__(256) void k_vtrans(const ushort_t* __restrict__ Vb,
                                                ushort_t* __restrict__ Vt) {
  __shared__ ushort_t t[32][33];
  int bx = blockIdx.x * 32, by = blockIdx.y * 32, b = blockIdx.z;
  int tx = threadIdx.x, ty = threadIdx.y;  // 32 x 8
#pragma unroll
  for (int r = 0; r < 32; r += 8)
    t[ty + r][tx] = Vb[((size_t)(b * S_ + by + ty + r)) * D_ + bx + tx];
  __syncthreads();
#pragma unroll
  for (int r = 0; r < 32; r += 8)
    Vt[((size_t)(b * D_ + bx + ty + r)) * S_ + by + tx] = t[tx][ty + r];
}

// ================= fused QKV GEMM: C = A[4096 x 2048*segs] * [Wq|Wk|Wv]^T =========
// 256x256 tile, BK=32, 512 thr = 8 waves (2M x 4N), per-wave 128x64 output.
// R5: REGISTER-double-buffered fragments (the m201 mechanism). Per tile kt:
//   1. issue 12 ds_reads for tile kt+1 (buf[(kt+1)&3] -- resident, see vmcnt inv.)
//   2. issue 4 gl_lds stages for tile kt+4 into buf[kt&3]
//   3. 32 MFMA on the register set loaded during tile kt-1 (NO lgkm wait in front;
//      those reads were lgkm(0)-confirmed before the end-of-(kt-1) barrier)
//   4. lgkmcnt(0)   -- step-1 reads drained under the MFMA cluster
//      vmcnt(8)     -- leaves kt+3,kt+4 stages in flight; proves kt+2 RESIDENT,
//                      which is exactly what tile kt+1's step-1 read-ahead needs
//      s_barrier    -- one per tile
// Race-freedom: reads FROM buf[kt&3] (read-ahead during kt-1) complete before the
// end-of-(kt-1) barrier (the lgkm(0)); stores into buf[kt&3] (stage of kt+4) are
// issued after that barrier. 4 buffers: read/next-resident/landing/staging disjoint.
// Tail: vmcnt 8 -> 4 -> 0 over the last tiles; x2-unrolled loop, NAMED reg sets.
// Swizzle: 16B-slot s of row r holds global slot s^((r>>1)&3); read slot
// koff = (quad ^ ((l16>>1)&3))*8 inverts it. 2-way max bank aliasing (free).
// N-concat: bx<8 -> Q (3 K-segs: (Ah,Wh),(Al,Wh),(Ah,Wl)); bx<16 -> K (2); else V.

__device__ inline void stage32(const ushort_t* __restrict__ g, int rowbase,
                               ushort_t* ldsTile, int tid) {
  const int rr = tid >> 2;                               // row 0..127 in chunk
  const int gs = ((tid & 3) ^ ((rr >> 1) & 3)) * 8;      // swizzled source slot
  gl_lds16(g + (size_t)(rowbase + rr) * D_ + gs,
           ldsTile + rowbase * 32 + (tid >> 6) * 512);   // wave-uniform LDS base
}

__global__ __launch_bounds__(512) void k_qkv(
    const ushort_t* __restrict__ Ah, const ushort_t* __restrict__ Al,
    const ushort_t* __restrict__ WqH, const ushort_t* __restrict__ WqL,
    const ushort_t* __restrict__ WkH, const ushort_t* __restrict__ WvH,
    ushort_t* __restrict__ Qh, ushort_t* __restrict__ Ql,
    ushort_t* __restrict__ Ko, ushort_t* __restrict__ Vo) {
  __shared__ ushort_t As_[4][256 * 32];  // 64 KB
  __shared__ ushort_t Bs_[4][256 * 32];  // 64 KB
  const int tid = threadIdx.x;
  const int wave = tid >> 6, lane = tid & 63;
  const int quad = lane >> 4, l16 = lane & 15;

  // bijective remap: XCD g (= orig linear id % 8) owns new ids g*48..g*48+47
  const int lid = blockIdx.y * 24 + blockIdx.x;
  const int nlid = (lid & 7) * 48 + (lid >> 3);
  const int bx = nlid % 24, by = nlid / 24;
  const int m0 = by * 256;
  const int wtype = bx >> 3;            // 0=Q 1=K 2=V
  const int n0 = (bx & 7) * 256;
  const int nseg = (wtype == 0) ? 3 : (wtype == 1) ? 2 : 1;
  const ushort_t* Bh0 = (wtype == 0) ? WqH : (wtype == 1) ? WkH : WvH;
  const int NT = nseg << 6;             // K-tiles of 32 (64/128/192, always even)

  const int wrM = (wave >> 2) * 128;    // 0 or 128
  const int wcN = (wave & 3) * 64;      // 0,64,128,192
  const int koff = (quad ^ ((l16 >> 1) & 3)) * 8;  // per-thread constant read slot

  // ---- prologue: stage tiles 0..3 (all segment 0; NT >= 64) ----
  {
    const ushort_t* Ap = Ah + (size_t)m0 * D_;
    const ushort_t* Bp = Bh0 + (size_t)n0 * D_;
#pragma unroll
    for (int t = 0; t < 4; ++t) {
      stage32(Ap + t * 32, 0,   &As_[t][0], tid);
      stage32(Ap + t * 32, 128, &As_[t][0], tid);
      stage32(Bp + t * 32, 0,   &Bs_[t][0], tid);
      stage32(Bp + t * 32, 128, &Bs_[t][0], tid);
    }
  }
  asm volatile("s_waitcnt vmcnt(12)" ::: "memory");  // tile 0 landed
  __builtin_amdgcn_s_barrier();
  asm volatile("" ::: "memory");

  s16x8 afA[8], bfA[4], afB[8], bfB[4];
  // read-ahead tile 0 -> set A
#pragma unroll
  for (int a = 0; a < 8; ++a)
    afA[a] = *(const s16x8*)(&As_[0][0] + (wrM + a * 16 + l16) * 32 + koff);
#pragma unroll
  for (int nt = 0; nt < 4; ++nt)
    bfA[nt] = *(const s16x8*)(&Bs_[0][0] + (wcN + nt * 16 + l16) * 32 + koff);
  asm volatile("s_waitcnt lgkmcnt(0)" ::: "memory");
  asm volatile("s_waitcnt vmcnt(8)" ::: "memory");   // tiles 0,1 resident
  __builtin_amdgcn_s_barrier();
  asm volatile("" ::: "memory");

  f32x4 acc[8][4] = {};

#define QKV_TILE_BODY(AFC, BFC, AFN, BFN)                                      \
  do {                                                                         \
    const bool doRd = (kt + 1 < NT);                                           \
    if (doRd) {                                                                \
      const ushort_t* Ab = &As_[(kt + 1) & 3][0];                              \
      const ushort_t* Bb = &Bs_[(kt + 1) & 3][0];                              \
      _Pragma("unroll") for (int a = 0; a < 8; ++a)                            \
        AFN[a] = *(const s16x8*)(Ab + (wrM + a * 16 + l16) * 32 + koff);       \
      _Pragma("unroll") for (int nt = 0; nt < 4; ++nt)                         \
        BFN[nt] = *(const s16x8*)(Bb + (wcN + nt * 16 + l16) * 32 + koff);     \
    }                                                                          \
    {                                                                          \
      const int st = kt + 4;                                                   \
      if (st < NT) {                                                           \
        const int sg = st >> 6, so = (st & 63) * 32;                           \
        const ushort_t* Asrc = ((sg == 1) ? Al : Ah) + (size_t)m0 * D_ + so;   \
        const ushort_t* Bsrc = ((sg == 2) ? WqL : Bh0) + (size_t)n0 * D_ + so; \
        ushort_t* Ad = &As_[kt & 3][0];                                        \
        ushort_t* Bd = &Bs_[kt & 3][0];                                        \
        stage32(Asrc, 0, Ad, tid);                                             \
        stage32(Asrc, 128, Ad, tid);                                           \
        stage32(Bsrc, 0, Bd, tid);                                             \
        stage32(Bsrc, 128, Bd, tid);                                           \
      }                                                                        \
    }                                                                          \
    __builtin_amdgcn_sched_barrier(0);                                         \
    __builtin_amdgcn_s_setprio(1);                                             \
    _Pragma("unroll") for (int a = 0; a < 8; ++a)                              \
      _Pragma("unroll") for (int nt = 0; nt < 4; ++nt)                         \
        acc[a][nt] = mfma_bf16(AFC[a], BFC[nt], acc[a][nt]);                   \
    __builtin_amdgcn_s_setprio(0);                                             \
    if (doRd) asm volatile("s_waitcnt lgkmcnt(0)" ::: "memory");               \
    if (kt <= NT - 5)                                                          \
      asm volatile("s_waitcnt vmcnt(8)" ::: "memory");                         \
    else if (kt == NT - 4)                                                     \
      asm volatile("s_waitcnt vmcnt(4)" ::: "memory");                         \
    else                                                                       \
      asm volatile("s_waitcnt vmcnt(0)" ::: "memory");                         \
    __builtin_amdgcn_s_barrier();                                              \
    asm volatile("" ::: "memory");                                             \
    ++kt;                                                                      \
  } while (0)

  int kt = 0;
  while (kt < NT) {
    QKV_TILE_BODY(afA, bfA, afB, bfB);
    QKV_TILE_BODY(afB, bfB, afA, bfA);
  }
#undef QKV_TILE_BODY

  // ---- epilogue: wave writes its 128x64 sub-tile ----
#pragma unroll
  for (int a = 0; a < 8; ++a)
#pragma unroll
    for (int nt = 0; nt < 4; ++nt)
#pragma unroll
      for (int r = 0; r < 4; ++r) {
        const int row = m0 + wrM + a * 16 + quad * 4 + r;
        const int col = n0 + wcN + nt * 16 + l16;
        const float v = acc[a][nt][r];
        const size_t idx = (size_t)row * D_ + col;
        if (wtype == 0) {
          unsigned short h = f2b(v);
          Qh[idx] = h;
          Ql[idx] = f2b(v - b2f(h));
        } else if (wtype == 1) {
          Ko[idx] = f2b(v);
        } else {
          Vo[idx] = f2b(v);
        }
      }
}

// ================= O-projection GEMM (R1 rotation, R4 minimal barriers) =========
__device__ inline void stage_chunk(const ushort_t* __restrict__ gbase, int K,
                                   int rowbase, ushort_t* ldsTile, int tid) {
  const int rr = tid >> 3;                       // row within 64-row chunk
  const int gs = ((tid & 7) ^ (rr & 7)) * 8;     // swizzled source 16B-slot
  gl_lds16(gbase + (size_t)(rowbase + rr) * K + gs,
           ldsTile + rowbase * 64 + (tid >> 6) * 512);  // wave-uniform LDS base
}

template <int NSEG, int OUT>
__global__ __launch_bounds__(512) void k_gemm8(
    const ushort_t* __restrict__ A0, const ushort_t* __restrict__ A1,
    const ushort_t* __restrict__ A2, const ushort_t* __restrict__ B0,
    const ushort_t* __restrict__ B2, ushort_t* __restrict__ Co,
    ushort_t* __restrict__ Col, float* __restrict__ Cf,
    const float* __restrict__ bias, int M, int N, int K) {
  __shared__ ushort_t As_[3][256 * 64];  // 96 KB
  __shared__ ushort_t Bs_[3][128 * 64];  // 48 KB
  const int tid = threadIdx.x;
  const int wave = tid >> 6, lane = tid & 63;
  const int quad = lane >> 4, l16 = lane & 15;
  const int m0 = blockIdx.y * 256, n0 = blockIdx.x * 128;
  const int wrM = (wave >> 1) * 64;  // 0,64,128,192
  const int wcN = (wave & 1) * 64;   // 0,64
  const int aRowB = (wrM + l16) * 64;
  const int bRowB = (wcN + l16) * 64;
  int ks8[2];
  ks8[0] = ((0 + quad) ^ (l16 & 7)) * 8;
  ks8[1] = ((4 + quad) ^ (l16 & 7)) * 8;
  const int NT = NSEG * 32;

  {
    const ushort_t* Ab0 = A0 + (size_t)m0 * K;
    const ushort_t* Bb0 = B0 + (size_t)n0 * K;
#pragma unroll
    for (int t = 0; t < 2; ++t) {
      const ushort_t* Ab = Ab0 + t * 64;
      const ushort_t* Bb = Bb0 + t * 64;
      stage_chunk(Ab, K, 0,   &As_[t][0], tid);
      stage_chunk(Ab, K, 64,  &As_[t][0], tid);
      stage_chunk(Ab, K, 128, &As_[t][0], tid);
      stage_chunk(Ab, K, 192, &As_[t][0], tid);
      stage_chunk(Bb, K, 0,   &Bs_[t][0], tid);
      stage_chunk(Bb, K, 64,  &Bs_[t][0], tid);
    }
  }
  asm volatile("s_waitcnt vmcnt(6)" ::: "memory");
  __builtin_amdgcn_s_barrier();
  asm volatile("" ::: "memory");

  f32x4 acc[4][4] = {};
  int cur = 0;
  for (int kt = 0; kt < NT; ++kt) {
    const int st = kt + 2;
    const bool doStage = (st < NT);
    int sbuf = cur + 2; if (sbuf >= 3) sbuf -= 3;
    ushort_t* At  = &As_[cur][0];
    ushort_t* Bt  = &Bs_[cur][0];
    ushort_t* Ads = &As_[sbuf][0];
    ushort_t* Bds = &Bs_[sbuf][0];
    const ushort_t* Asb = A0;
    const ushort_t* Bsb = B0;
    if (doStage) {
      const int sg = st >> 5;
      const ushort_t* Ag = A0;
      const ushort_t* Bg = B0;
      if (NSEG >= 2 && sg == 1) Ag = A1;
      if (NSEG == 3 && sg == 2) { Ag = A2; Bg = B2; }
      Asb = Ag + (size_t)m0 * K + (size_t)(st & 31) * 64;
      Bsb = Bg + (size_t)n0 * K + (size_t)(st & 31) * 64;
    }
    s16x8 bf[4][2];
#pragma unroll
    for (int p = 0; p < 2; ++p) {
      s16x8 af[2][2];
#pragma unroll
      for (int i = 0; i < 2; ++i)
#pragma unroll
        for (int s = 0; s < 2; ++s)
          af[i][s] = *(const s16x8*)(At + aRowB + (p * 2 + i) * 1024 + ks8[s]);
      if (p == 0) {
#pragma unroll
        for (int nt = 0; nt < 4; ++nt)
#pragma unroll
          for (int s = 0; s < 2; ++s)
            bf[nt][s] = *(const s16x8*)(Bt + bRowB + nt * 1024 + ks8[s]);
      }
      if (doStage) {
        if (p == 0) {
          stage_chunk(Asb, K, 0,   Ads, tid);
          stage_chunk(Asb, K, 64,  Ads, tid);
          stage_chunk(Asb, K, 128, Ads, tid);
        } else {
          stage_chunk(Asb, K, 192, Ads, tid);
          stage_chunk(Bsb, K, 0,   Bds, tid);
          stage_chunk(Bsb, K, 64,  Bds, tid);
        }
      }
      asm volatile("s_waitcnt lgkmcnt(0)" ::: "memory");
      __builtin_amdgcn_sched_barrier(0);
      __builtin_amdgcn_s_setprio(1);
#pragma unroll
      for (int i = 0; i < 2; ++i)
#pragma unroll
        for (int nt = 0; nt < 4; ++nt)
#pragma unroll
          for (int s = 0; s < 2; ++s)
            acc[p * 2 + i][nt] = mfma_bf16(af[i][s], bf[nt][s], acc[p * 2 + i][nt]);
      __builtin_amdgcn_s_setprio(0);
      if (p == 1) {
        if (doStage) asm volatile("s_waitcnt vmcnt(6)" ::: "memory");
        else         asm volatile("s_waitcnt vmcnt(0)" ::: "memory");
        __builtin_amdgcn_s_barrier();
        asm volatile("" ::: "memory");
      }
    }
    cur = (cur == 2) ? 0 : cur + 1;
  }

#pragma unroll
  for (int mt = 0; mt < 4; ++mt)
#pragma unroll
    for (int nt = 0; nt < 4; ++nt)
#pragma unroll
      for (int r = 0; r < 4; ++r) {
        int row = m0 + wrM + mt * 16 + quad * 4 + r;
        int col = n0 + wcN + nt * 16 + l16;
        float v = acc[mt][nt][r];
        if (OUT == 2) {
          Cf[(size_t)row * N + col] = v + bias[col];
        } else if (OUT == 1) {
          unsigned short h = f2b(v);
          Co[(size_t)row * N + col]  = h;
          Col[(size_t)row * N + col] = f2b(v - b2f(h));
        } else {
          Co[(size_t)row * N + col] = f2b(v);
        }
      }
}

// ---------------- MFMA flash attention, 64-query tile per block ----------------
__global__ __launch_bounds__(256) void k_fattn(const ushort_t* __restrict__ Qh,
                                               const ushort_t* __restrict__ Ql,
                                               const ushort_t* __restrict__ Kh,
                                               const ushort_t* __restrict__ Vt,
                                               const int* __restrict__ amask,
                                               ushort_t* __restrict__ AO) {
  __shared__ ushort_t Ksh[64][136];
  __shared__ ushort_t Vs[128][72];
  __shared__ ushort_t ps[4][16][72];
  __shared__ int ams[320];
  const int tid = threadIdx.x;
  const int wave = tid >> 6, lane = tid & 63;
  const int quad = lane >> 4, l16 = lane & 15;
  const int qt = blockIdx.x, h = blockIdx.y, b = blockIdx.z;
  const int q0 = qt * 64;

  for (int x = tid; x < 320; x += 256) {
    int j = q0 - 256 + x;
    ams[x] = (j >= 0) ? amask[b * S_ + j] : 0;
  }

  const int qrowA = q0 + wave * 16 + l16;
  const ushort_t* qbh = Qh + ((size_t)(b * S_ + qrowA) * D_) + h * HD_;
  const ushort_t* qbl = Ql + ((size_t)(b * S_ + qrowA) * D_) + h * HD_;
  s16x8 qh[4], ql[4];
#pragma unroll
  for (int kk = 0; kk < 4; kk++) {
    qh[kk] = *(const s16x8*)(qbh + kk * 32 + quad * 8);
    ql[kk] = *(const s16x8*)(qbl + kk * 32 + quad * 8);
  }

  f32x4 O[8] = {};
  float m_run[4], l_run[4];
#pragma unroll
  for (int r = 0; r < 4; r++) { m_run[r] = -3.0e38f; l_run[r] = 0.f; }

  const int t0 = (qt < 4) ? (4 - qt) : 0;
  for (int t = t0; t < 5; t++) {
    const int kb = q0 - 256 + 64 * t;
    __syncthreads();
    {
      const int key = tid >> 2, dimb = (tid & 3) * 32;
      const ushort_t* kgh = Kh + ((size_t)(b * S_ + kb + key) * D_) + h * HD_ + dimb;
#pragma unroll
      for (int u = 0; u < 4; u++)
        *(uint4*)&Ksh[key][dimb + u * 8] = *(const uint4*)(kgh + u * 8);
      const int hd = tid >> 1, keyb = (tid & 1) * 32;
      const ushort_t* vg = Vt + ((size_t)(b * D_ + h * HD_ + hd) * S_) + kb + keyb;
#pragma unroll
      for (int u = 0; u < 4; u++)
        *(uint4*)&Vs[hd][keyb + u * 8] = *(const uint4*)(vg + u * 8);
    }
    __syncthreads();

    f32x4 sacc[4] = {};
#pragma unroll
    for (int kk = 0; kk < 4; kk++)
#pragma unroll
      for (int nt = 0; nt < 4; nt++) {
        s16x8 kfh = *(const s16x8*)&Ksh[nt * 16 + l16][kk * 32 + quad * 8];
        sacc[nt] = mfma_bf16(qh[kk], kfh, sacc[nt]);
        sacc[nt] = mfma_bf16(ql[kk], kfh, sacc[nt]);
      }

#pragma unroll
    for (int nt = 0; nt < 4; nt++) {
      const int j = kb + nt * 16 + l16;
      const bool amok = ams[64 * t + nt * 16 + l16] != 0;
#pragma unroll
      for (int r = 0; r < 4; r++) {
        const int iq = q0 + wave * 16 + quad * 4 + r;
        const bool ok = amok && (j <= iq) && (j > iq - WIN_);
        if (!ok) sacc[nt][r] = -3.0e38f;
      }
    }
    float mt[4];
#pragma unroll
    for (int r = 0; r < 4; r++) {
      mt[r] = fmaxf(fmaxf(sacc[0][r], sacc[1][r]), fmaxf(sacc[2][r], sacc[3][r]));
      mt[r] = fmaxf(mt[r], __shfl_xor(mt[r], 1));
      mt[r] = fmaxf(mt[r], __shfl_xor(mt[r], 2));
      mt[r] = fmaxf(mt[r], __shfl_xor(mt[r], 4));
      mt[r] = fmaxf(mt[r], __shfl_xor(mt[r], 8));
    }
    float alpha[4], lt[4];
#pragma unroll
    for (int r = 0; r < 4; r++) {
      float mnew = fmaxf(m_run[r], mt[r]);
      alpha[r] = __expf(m_run[r] - mnew);
      m_run[r] = mnew;
      lt[r] = 0.f;
#pragma unroll
      for (int nt = 0; nt < 4; nt++) {
        float s = sacc[nt][r];
        float p = (s > -1.0e30f) ? __expf(s - mnew) : 0.f;
        sacc[nt][r] = p;
        lt[r] += p;
      }
      lt[r] += __shfl_xor(lt[r], 1);
      lt[r] += __shfl_xor(lt[r], 2);
      lt[r] += __shfl_xor(lt[r], 4);
      lt[r] += __shfl_xor(lt[r], 8);
      l_run[r] = l_run[r] * alpha[r] + lt[r];
    }
#pragma unroll
    for (int o = 0; o < 8; o++)
#pragma unroll
      for (int r = 0; r < 4; r++) O[o][r] *= alpha[r];
#pragma unroll
    for (int nt = 0; nt < 4; nt++)
#pragma unroll
      for (int r = 0; r < 4; r++)
        ps[wave][quad * 4 + r][nt * 16 + l16] = f2b(sacc[nt][r]);
    __syncthreads();
#pragma unroll
    for (int kk2 = 0; kk2 < 2; kk2++) {
      s16x8 pf = *(const s16x8*)&ps[wave][l16][kk2 * 32 + quad * 8];
#pragma unroll
      for (int o = 0; o < 8; o++) {
        s16x8 vf = *(const s16x8*)&Vs[o * 16 + l16][kk2 * 32 + quad * 8];
        O[o] = mfma_bf16(pf, vf, O[o]);
      }
    }
  }
#pragma unroll
  for (int r = 0; r < 4; r++) l_run[r] = 1.0f / l_run[r];
#pragma unroll
  for (int o = 0; o < 8; o++)
#pragma unroll
    for (int r = 0; r < 4; r++) {
      int row = q0 + wave * 16 + quad * 4 + r;
      AO[((size_t)(b * S_ + row) * D_) + h * HD_ + o * 16 + l16] = f2b(O[o][r] * l_run[r]);
    }
}

extern "C" void kernel_launch(void* const* d_in, const int* in_sizes, int n_in,
                              void* d_out, int out_size, void* d_ws, size_t ws_size,
                              hipStream_t stream) {
  const float* hs    = (const float*)d_in[0];
  const int*   amask = (const int*)d_in[1];
  const float* Wq    = (const float*)d_in[2];
  const float* Wk    = (const float*)d_in[3];
  const float* Wv    = (const float*)d_in[4];
  const float* Wo    = (const float*)d_in[5];
  const float* bo    = (const float*)d_in[6];
  float* out = (float*)d_out;

  char* p = (char*)d_ws;
  ushort_t* hsHi = (ushort_t*)p; p += (size_t)16 << 20;
  ushort_t* hsLo = (ushort_t*)p; p += (size_t)16 << 20;
  ushort_t* WqTh = (ushort_t*)p; p += (size_t)8 << 20;
  ushort_t* WqTl = (ushort_t*)p; p += (size_t)8 << 20;
  ushort_t* WkTh = (ushort_t*)p; p += (size_t)8 << 20;
  ushort_t* WkTl = (ushort_t*)p; p += (size_t)8 << 20;  (void)WkTl;
  ushort_t* WvTh = (ushort_t*)p; p += (size_t)8 << 20;
  ushort_t* WoTh = (ushort_t*)p; p += (size_t)8 << 20;
  ushort_t* Qhb  = (ushort_t*)p; p += (size_t)16 << 20;
  ushort_t* Qlb  = (ushort_t*)p; p += (size_t)16 << 20;
  ushort_t* Khb  = (ushort_t*)p; p += (size_t)16 << 20;
  ushort_t* Vb   = (ushort_t*)p; p += (size_t)16 << 20;
  ushort_t* Vt   = (ushort_t*)p; p += (size_t)16 << 20;

  k_split<<<M_ * D_ / 1024, 256, 0, stream>>>(hs, hsHi, hsLo, M_ * D_);
  dim3 tb(32, 8), tg4(D_ / 32, D_ / 32, 4);
  k_transpose4<<<tg4, tb, 0, stream>>>(Wq, Wk, Wv, Wo, WqTh, WqTl, WkTh, nullptr, WvTh, WoTh);

  // fused QKV: grid (24,16) = 384 blocks; bx<8 Q (3 segs), <16 K (2), else V (1)
  dim3 gq(24, 16);
  k_qkv<<<gq, 512, 0, stream>>>(hsHi, hsLo, WqTh, WqTl, WkTh, WvTh, Qhb, Qlb, Khb, Vb);

  dim3 vg(D_ / 32, S_ / 32, B_);
  k_vtrans<<<vg, tb, 0, stream>>>(Vb, Vt);

  dim3 ag(S_ / 64, H_, B_);  // (32, 16, 2)
  k_fattn<<<ag, 256, 0, stream>>>(Qhb, Qlb, Khb, Vt, amask, hsHi /*AO*/);

  // O: plain, f32 + bias epilogue (256x128 tile)
  dim3 gg(D_ / 128, M_ / 256);
  k_gemm8<1, 2><<<gg, 512, 0, stream>>>(hsHi /*AO*/, nullptr, nullptr, WoTh, nullptr,
                                        nullptr, nullptr, out, bo, M_, D_, D_);
}

// Round 6
// 426.682 us; speedup vs baseline: 1.0612x; 1.0612x over previous
//
#include <hip/hip_runtime.h>

#define B_   2
#define S_   2048
#define D_   2048
#define H_   16
#define HD_  128
#define WIN_ 256
#define M_   (B_ * S_)  // 4096

typedef float  f32x4  __attribute__((ext_vector_type(4)));
typedef short  s16x8  __attribute__((ext_vector_type(8)));
typedef __bf16 bf16x8 __attribute__((ext_vector_type(8)));
typedef unsigned short ushort_t;

__device__ inline unsigned short f2b(float f) {
  unsigned u = __builtin_bit_cast(unsigned, f);
  u += 0x7fffu + ((u >> 16) & 1u);  // RNE
  return (unsigned short)(u >> 16);
}
__device__ inline float b2f(unsigned short h) {
  unsigned u = ((unsigned)h) << 16;
  return __builtin_bit_cast(float, u);
}

// Hedged MFMA call: gfx950 builtin may take v8bf16 (upstream clang) or v8i16.
template <typename T>
__device__ auto mfma_impl(T a, T b, f32x4 c, int)
    -> decltype(__builtin_amdgcn_mfma_f32_16x16x32_bf16(a, b, c, 0, 0, 0)) {
  return __builtin_amdgcn_mfma_f32_16x16x32_bf16(a, b, c, 0, 0, 0);
}
template <typename T>
__device__ f32x4 mfma_impl(T a, T b, f32x4 c, long) {
  return __builtin_amdgcn_mfma_f32_16x16x32_bf16(
      __builtin_bit_cast(bf16x8, a), __builtin_bit_cast(bf16x8, b), c, 0, 0, 0);
}
__device__ inline f32x4 mfma_bf16(s16x8 a, s16x8 b, f32x4 c) {
  return mfma_impl(a, b, c, 0);
}

// ---- async global->LDS, 16B/lane. lds base must be wave-uniform; lane i lands at +i*16B.
#if defined(__has_builtin)
#if __has_builtin(__builtin_amdgcn_global_load_lds)
#define HAS_GLL 1
#endif
#endif
#ifndef HAS_GLL
#define HAS_GLL 0
#endif

__device__ inline void gl_lds16(const ushort_t* g, ushort_t* lds_wave_base) {
#if HAS_GLL
  __builtin_amdgcn_global_load_lds(
      (const __attribute__((address_space(1))) unsigned int*)g,
      (__attribute__((address_space(3))) unsigned int*)lds_wave_base, 16, 0, 0);
#else
  const int lane = threadIdx.x & 63;
  *(uint4*)(lds_wave_base + lane * 8) = *(const uint4*)g;
#endif
}

// ---------------- split f32 -> bf16 hi + lo ----------------
__global__ __launch_bounds__(256) void k_split(const float* __restrict__ x,
                                               ushort_t* __restrict__ hi,
                                               ushort_t* __restrict__ lo, int n) {
  int i = (blockIdx.x * 256 + threadIdx.x) * 4;
  if (i + 3 < n) {
    float4 v = *(const float4*)(x + i);
    ushort4 h, l;
    h.x = f2b(v.x); l.x = f2b(v.x - b2f(h.x));
    h.y = f2b(v.y); l.y = f2b(v.y - b2f(h.y));
    h.z = f2b(v.z); l.z = f2b(v.z - b2f(h.z));
    h.w = f2b(v.w); l.w = f2b(v.w - b2f(h.w));
    *(ushort4*)(hi + i) = h;
    *(ushort4*)(lo + i) = l;
  }
}

// ---------------- fused transpose + split of all 4 weights: z picks W ----------------
__global__ __launch_bounds__(256) void k_transpose4(const float* __restrict__ W0,
                                                    const float* __restrict__ W1,
                                                    const float* __restrict__ W2,
                                                    const float* __restrict__ W3,
                                                    ushort_t* __restrict__ T0h,
                                                    ushort_t* __restrict__ T0l,
                                                    ushort_t* __restrict__ T1h,
                                                    ushort_t* __restrict__ T1l,
                                                    ushort_t* __restrict__ T2h,
                                                    ushort_t* __restrict__ T3h) {
  __shared__ float t[32][33];
  const int z = blockIdx.z;
  const float* W = (z == 0) ? W0 : (z == 1) ? W1 : (z == 2) ? W2 : W3;
  ushort_t* Th = (z == 0) ? T0h : (z == 1) ? T1h : (z == 2) ? T2h : T3h;
  ushort_t* Tl = (z == 0) ? T0l : (z == 1) ? T1l : nullptr;
  int bx = blockIdx.x * 32, by = blockIdx.y * 32;
  int tx = threadIdx.x, ty = threadIdx.y;  // 32 x 8
#pragma unroll
  for (int r = 0; r < 32; r += 8)
    t[ty + r][tx] = W[(size_t)(by + ty + r) * D_ + bx + tx];
  __syncthreads();
#pragma unroll
  for (int r = 0; r < 32; r += 8) {
    float v = t[tx][ty + r];
    unsigned short h = f2b(v);
    Th[(size_t)(bx + ty + r) * D_ + by + tx] = h;
    if (Tl) Tl[(size_t)(bx + ty + r) * D_ + by + tx] = f2b(v - b2f(h));
  }
}

// ---------------- bf16 transpose for V: Vt[b*D + c][s] = Vb[b*S + s][c] ----------------
__global__ __launch_bounds__(256) void k_vtrans(const ushort_t* __restrict__ Vb,
                                                ushort_t* __restrict__ Vt) {
  __shared__ ushort_t t[32][33];
  int bx = blockIdx.x * 32, by = blockIdx.y * 32, b = blockIdx.z;
  int tx = threadIdx.x, ty = threadIdx.y;  // 32 x 8
#pragma unroll
  for (int r = 0; r < 32; r += 8)
    t[ty + r][tx] = Vb[((size_t)(b * S_ + by + ty + r)) * D_ + bx + tx];
  __syncthreads();
#pragma unroll
  for (int r = 0; r < 32; r += 8)
    Vt[((size_t)(b * D_ + bx + ty + r)) * S_ + by + tx] = t[tx][ty + r];
}

// ================= fused QKV GEMM -- m201-style 8-phase schedule ==================
// 256x256 tile, BK=64, 512 thr = 8 waves (2M x 4N), per-wave 128x64 output.
// 2 LDS double-buffers per operand (A: 2x[256][64], B: 2x[256][64] = 128 KB).
// Iteration i computes tiles t0=2i (dbuf0) over phases 1-4 and t1=2i+1 (dbuf1)
// over phases 5-8. Phase = {ds_reads for THIS phase's MFMAs; stage ONE half-tile
// (2x global_load_lds); s_barrier; lgkmcnt(0); sched_barrier(0); setprio(1);
// 16 MFMA; setprio(0); [ph4/ph8: counted vmcnt]; s_barrier}.
// Stage stream (one half per phase): ph1: t1.Alo  ph2: t1.Ahi  ph3: T2.Blo
// ph4: T2.Bhi  ph5: T2.Alo  ph6: T2.Ahi  ph7: T3.Blo  ph8: T3.Bhi  (T2=2i+2,
// T3=2i+3; T3.A goes at next iter's ph1/ph2 as "t1.A").
// Safety (derived, all cases checked): a stage into buffer-half X is issued >=1
// phase after the last ds_read of X's previous occupant (that read is lgkm(0)-
// confirmed before the intervening barrier); vmcnt(4) at ph4-end confirms all of
// t1 before ph5 reads it; vmcnt(4) at ph8-end confirms all of T2 before next
// iter's ph1. Tail (last iter): no T2/T3 stages, vmcnt(0) at ph4-end.
// Swizzle (128B rows): store 16B-slot s of row r at s^(r&7) via pre-swizzled
// GLOBAL source (linear gl_lds dest); read slot (kk*4+quad)^(l16&7) inverts it.
// 2-way max bank aliasing (free, m136).
// N-concat: bx<8 -> Q (3 K-segs: (Ah,Wh),(Al,Wh),(Ah,Wl)); bx<16 -> K (2); else V.

__device__ inline void stage64(const ushort_t* __restrict__ g, int rowbase,
                               ushort_t* ldsTile, int tid) {
  const int r = tid >> 3;                              // row 0..63 within call
  const int gs = ((tid & 7) ^ (r & 7)) * 8;            // swizzled source slot
  gl_lds16(g + (size_t)(rowbase + r) * D_ + gs,
           ldsTile + rowbase * 64 + (tid >> 6) * 512); // wave-uniform LDS base
}

__global__ __launch_bounds__(512) void k_qkv(
    const ushort_t* __restrict__ Ah, const ushort_t* __restrict__ Al,
    const ushort_t* __restrict__ WqH, const ushort_t* __restrict__ WqL,
    const ushort_t* __restrict__ WkH, const ushort_t* __restrict__ WvH,
    ushort_t* __restrict__ Qh, ushort_t* __restrict__ Ql,
    ushort_t* __restrict__ Ko, ushort_t* __restrict__ Vo) {
  __shared__ ushort_t Ab_[2][256 * 64];  // 64 KB
  __shared__ ushort_t Bb_[2][256 * 64];  // 64 KB
  const int tid = threadIdx.x;
  const int wave = tid >> 6, lane = tid & 63;
  const int quad = lane >> 4, l16 = lane & 15;

  // bijective remap: XCD g (= orig linear id % 8) owns 2 contiguous M-panels.
  const int lid = blockIdx.y * 24 + blockIdx.x;
  const int nlid = (lid & 7) * 48 + (lid >> 3);
  const int bx = nlid % 24, by = nlid / 24;
  const int m0 = by * 256;
  const int wtype = bx >> 3;            // 0=Q 1=K 2=V
  const int n0 = (bx & 7) * 256;
  const int nseg = (wtype == 0) ? 3 : (wtype == 1) ? 2 : 1;
  const ushort_t* Bh0 = (wtype == 0) ? WqH : (wtype == 1) ? WkH : WvH;
  const int NT = nseg << 5;             // K64-tiles (32 per K=2048 segment)
  const int NI = NT >> 1;               // iterations (2 tiles each)

  const int wrM = (wave >> 2) * 128;    // 0 or 128
  const int wcN = (wave & 3) * 64;      // 0,64,128,192
  const int ko0 = (quad ^ (l16 & 7)) * 8;        // kk=0 read slot (swizzled)
  const int ko1 = ((4 + quad) ^ (l16 & 7)) * 8;  // kk=1

#define SRC_A(t) ((((t) >> 5) == 1 ? Al : Ah) + (size_t)m0 * D_ + ((t) & 31) * 64)
#define SRC_B(t) ((((t) >> 5) == 2 ? WqL : Bh0) + (size_t)n0 * D_ + ((t) & 31) * 64)
#define RD(buf, row, ko) (*(const s16x8*)((buf) + (row) * 64 + (ko)))

  // ---- prologue: T0 fully + T1.B halves; leave T1.B outstanding (steady state) ----
  {
    const ushort_t* sA0 = SRC_A(0);
    const ushort_t* sB0 = SRC_B(0);
    const ushort_t* sB1 = SRC_B(1);
    stage64(sA0, 0,   &Ab_[0][0], tid); stage64(sA0, 64,  &Ab_[0][0], tid);
    stage64(sA0, 128, &Ab_[0][0], tid); stage64(sA0, 192, &Ab_[0][0], tid);
    stage64(sB0, 0,   &Bb_[0][0], tid); stage64(sB0, 64,  &Bb_[0][0], tid);
    stage64(sB0, 128, &Bb_[0][0], tid); stage64(sB0, 192, &Bb_[0][0], tid);
    stage64(sB1, 0,   &Bb_[1][0], tid); stage64(sB1, 64,  &Bb_[1][0], tid);
    stage64(sB1, 128, &Bb_[1][0], tid); stage64(sB1, 192, &Bb_[1][0], tid);
  }
  asm volatile("s_waitcnt vmcnt(4)" ::: "memory");  // T0 landed; T1.B in flight
  __builtin_amdgcn_s_barrier();
  asm volatile("" ::: "memory");

#define PH_PRE()                                         \
  __builtin_amdgcn_s_barrier();                          \
  asm volatile("s_waitcnt lgkmcnt(0)" ::: "memory");     \
  __builtin_amdgcn_sched_barrier(0);                     \
  __builtin_amdgcn_s_setprio(1)
#define PH_POST()                                        \
  __builtin_amdgcn_s_setprio(0);                         \
  __builtin_amdgcn_s_barrier();                          \
  asm volatile("" ::: "memory")

  f32x4 acc[8][4] = {};
  s16x8 aF[4][2], bL[2][2], bH[2][2];

  for (int i = 0; i < NI; ++i) {
    const int t0 = 2 * i;
    const bool doSt = (i + 1 < NI);
    const ushort_t* A0 = &Ab_[0][0];
    const ushort_t* B0 = &Bb_[0][0];
    const ushort_t* A1 = &Ab_[1][0];
    const ushort_t* B1 = &Bb_[1][0];
    const ushort_t* sAt1 = SRC_A(t0 + 1);
    const ushort_t* sAt2 = SRC_A(t0 + 2);
    const ushort_t* sBt2 = SRC_B(t0 + 2);
    const ushort_t* sBt3 = SRC_B(t0 + 3);

    // ---------- phase 1: A-lo(t0) + B-lo(t0); stage t1.Alo ----------
#pragma unroll
    for (int f = 0; f < 4; ++f) {
      aF[f][0] = RD(A0, wrM + f * 16 + l16, ko0);
      aF[f][1] = RD(A0, wrM + f * 16 + l16, ko1);
    }
#pragma unroll
    for (int c = 0; c < 2; ++c) {
      bL[c][0] = RD(B0, wcN + c * 16 + l16, ko0);
      bL[c][1] = RD(B0, wcN + c * 16 + l16, ko1);
    }
    stage64(sAt1, 0, &Ab_[1][0], tid);
    stage64(sAt1, 64, &Ab_[1][0], tid);
    PH_PRE();
#pragma unroll
    for (int f = 0; f < 4; ++f)
#pragma unroll
      for (int c = 0; c < 2; ++c) {
        acc[f][c] = mfma_bf16(aF[f][0], bL[c][0], acc[f][c]);
        acc[f][c] = mfma_bf16(aF[f][1], bL[c][1], acc[f][c]);
      }
    PH_POST();

    // ---------- phase 2: B-hi(t0); stage t1.Ahi ----------
#pragma unroll
    for (int c = 0; c < 2; ++c) {
      bH[c][0] = RD(B0, wcN + 32 + c * 16 + l16, ko0);
      bH[c][1] = RD(B0, wcN + 32 + c * 16 + l16, ko1);
    }
    stage64(sAt1, 128, &Ab_[1][0], tid);
    stage64(sAt1, 192, &Ab_[1][0], tid);
    PH_PRE();
#pragma unroll
    for (int f = 0; f < 4; ++f)
#pragma unroll
      for (int c = 0; c < 2; ++c) {
        acc[f][2 + c] = mfma_bf16(aF[f][0], bH[c][0], acc[f][2 + c]);
        acc[f][2 + c] = mfma_bf16(aF[f][1], bH[c][1], acc[f][2 + c]);
      }
    PH_POST();

    // ---------- phase 3: A-hi(t0); stage T2.Blo ----------
#pragma unroll
    for (int f = 0; f < 4; ++f) {
      aF[f][0] = RD(A0, wrM + 64 + f * 16 + l16, ko0);
      aF[f][1] = RD(A0, wrM + 64 + f * 16 + l16, ko1);
    }
    if (doSt) {
      stage64(sBt2, 0, &Bb_[0][0], tid);
      stage64(sBt2, 64, &Bb_[0][0], tid);
    }
    PH_PRE();
#pragma unroll
    for (int f = 0; f < 4; ++f)
#pragma unroll
      for (int c = 0; c < 2; ++c) {
        acc[4 + f][c] = mfma_bf16(aF[f][0], bL[c][0], acc[4 + f][c]);
        acc[4 + f][c] = mfma_bf16(aF[f][1], bL[c][1], acc[4 + f][c]);
      }
    PH_POST();

    // ---------- phase 4: no reads; stage T2.Bhi; vmcnt ----------
    if (doSt) {
      stage64(sBt2, 128, &Bb_[0][0], tid);
      stage64(sBt2, 192, &Bb_[0][0], tid);
    }
    PH_PRE();
#pragma unroll
    for (int f = 0; f < 4; ++f)
#pragma unroll
      for (int c = 0; c < 2; ++c) {
        acc[4 + f][2 + c] = mfma_bf16(aF[f][0], bH[c][0], acc[4 + f][2 + c]);
        acc[4 + f][2 + c] = mfma_bf16(aF[f][1], bH[c][1], acc[4 + f][2 + c]);
      }
    __builtin_amdgcn_s_setprio(0);
    if (doSt) asm volatile("s_waitcnt vmcnt(4)" ::: "memory");
    else      asm volatile("s_waitcnt vmcnt(0)" ::: "memory");
    __builtin_amdgcn_s_barrier();
    asm volatile("" ::: "memory");

    // ---------- phase 5: A-lo(t1) + B-lo(t1); stage T2.Alo ----------
#pragma unroll
    for (int f = 0; f < 4; ++f) {
      aF[f][0] = RD(A1, wrM + f * 16 + l16, ko0);
      aF[f][1] = RD(A1, wrM + f * 16 + l16, ko1);
    }
#pragma unroll
    for (int c = 0; c < 2; ++c) {
      bL[c][0] = RD(B1, wcN + c * 16 + l16, ko0);
      bL[c][1] = RD(B1, wcN + c * 16 + l16, ko1);
    }
    if (doSt) {
      stage64(sAt2, 0, &Ab_[0][0], tid);
      stage64(sAt2, 64, &Ab_[0][0], tid);
    }
    PH_PRE();
#pragma unroll
    for (int f = 0; f < 4; ++f)
#pragma unroll
      for (int c = 0; c < 2; ++c) {
        acc[f][c] = mfma_bf16(aF[f][0], bL[c][0], acc[f][c]);
        acc[f][c] = mfma_bf16(aF[f][1], bL[c][1], acc[f][c]);
      }
    PH_POST();

    // ---------- phase 6: B-hi(t1); stage T2.Ahi ----------
#pragma unroll
    for (int c = 0; c < 2; ++c) {
      bH[c][0] = RD(B1, wcN + 32 + c * 16 + l16, ko0);
      bH[c][1] = RD(B1, wcN + 32 + c * 16 + l16, ko1);
    }
    if (doSt) {
      stage64(sAt2, 128, &Ab_[0][0], tid);
      stage64(sAt2, 192, &Ab_[0][0], tid);
    }
    PH_PRE();
#pragma unroll
    for (int f = 0; f < 4; ++f)
#pragma unroll
      for (int c = 0; c < 2; ++c) {
        acc[f][2 + c] = mfma_bf16(aF[f][0], bH[c][0], acc[f][2 + c]);
        acc[f][2 + c] = mfma_bf16(aF[f][1], bH[c][1], acc[f][2 + c]);
      }
    PH_POST();

    // ---------- phase 7: A-hi(t1); stage T3.Blo ----------
#pragma unroll
    for (int f = 0; f < 4; ++f) {
      aF[f][0] = RD(A1, wrM + 64 + f * 16 + l16, ko0);
      aF[f][1] = RD(A1, wrM + 64 + f * 16 + l16, ko1);
    }
    if (doSt) {
      stage64(sBt3, 0, &Bb_[1][0], tid);
      stage64(sBt3, 64, &Bb_[1][0], tid);
    }
    PH_PRE();
#pragma unroll
    for (int f = 0; f < 4; ++f)
#pragma unroll
      for (int c = 0; c < 2; ++c) {
        acc[4 + f][c] = mfma_bf16(aF[f][0], bL[c][0], acc[4 + f][c]);
        acc[4 + f][c] = mfma_bf16(aF[f][1], bL[c][1], acc[4 + f][c]);
      }
    PH_POST();

    // ---------- phase 8: no reads; stage T3.Bhi; vmcnt ----------
    if (doSt) {
      stage64(sBt3, 128, &Bb_[1][0], tid);
      stage64(sBt3, 192, &Bb_[1][0], tid);
    }
    PH_PRE();
#pragma unroll
    for (int f = 0; f < 4; ++f)
#pragma unroll
      for (int c = 0; c < 2; ++c) {
        acc[4 + f][2 + c] = mfma_bf16(aF[f][0], bH[c][0], acc[4 + f][2 + c]);
        acc[4 + f][2 + c] = mfma_bf16(aF[f][1], bH[c][1], acc[4 + f][2 + c]);
      }
    __builtin_amdgcn_s_setprio(0);
    if (doSt) {
      asm volatile("s_waitcnt vmcnt(4)" ::: "memory");
      __builtin_amdgcn_s_barrier();
      asm volatile("" ::: "memory");
    }
  }
#undef PH_PRE
#undef PH_POST
#undef SRC_A
#undef SRC_B
#undef RD

  // ---- epilogue: wave writes its 128x64 sub-tile ----
#pragma unroll
  for (int a = 0; a < 8; ++a)
#pragma unroll
    for (int nt = 0; nt < 4; ++nt)
#pragma unroll
      for (int r = 0; r < 4; ++r) {
        const int row = m0 + wrM + a * 16 + quad * 4 + r;
        const int col = n0 + wcN + nt * 16 + l16;
        const float v = acc[a][nt][r];
        const size_t idx = (size_t)row * D_ + col;
        if (wtype == 0) {
          unsigned short h = f2b(v);
          Qh[idx] = h;
          Ql[idx] = f2b(v - b2f(h));
        } else if (wtype == 1) {
          Ko[idx] = f2b(v);
        } else {
          Vo[idx] = f2b(v);
        }
      }
}

// ================= O-projection GEMM (unchanged) ====================
__device__ inline void stage_chunk(const ushort_t* __restrict__ gbase, int K,
                                   int rowbase, ushort_t* ldsTile, int tid) {
  const int rr = tid >> 3;                       // row within 64-row chunk
  const int gs = ((tid & 7) ^ (rr & 7)) * 8;     // swizzled source 16B-slot
  gl_lds16(gbase + (size_t)(rowbase + rr) * K + gs,
           ldsTile + rowbase * 64 + (tid >> 6) * 512);  // wave-uniform LDS base
}

template <int NSEG, int OUT>
__global__ __launch_bounds__(512) void k_gemm8(
    const ushort_t* __restrict__ A0, const ushort_t* __restrict__ A1,
    const ushort_t* __restrict__ A2, const ushort_t* __restrict__ B0,
    const ushort_t* __restrict__ B2, ushort_t* __restrict__ Co,
    ushort_t* __restrict__ Col, float* __restrict__ Cf,
    const float* __restrict__ bias, int M, int N, int K) {
  __shared__ ushort_t As_[3][256 * 64];  // 96 KB
  __shared__ ushort_t Bs_[3][128 * 64];  // 48 KB
  const int tid = threadIdx.x;
  const int wave = tid >> 6, lane = tid & 63;
  const int quad = lane >> 4, l16 = lane & 15;
  const int m0 = blockIdx.y * 256, n0 = blockIdx.x * 128;
  const int wrM = (wave >> 1) * 64;  // 0,64,128,192
  const int wcN = (wave & 1) * 64;   // 0,64
  const int aRowB = (wrM + l16) * 64;
  const int bRowB = (wcN + l16) * 64;
  int ks8[2];
  ks8[0] = ((0 + quad) ^ (l16 & 7)) * 8;
  ks8[1] = ((4 + quad) ^ (l16 & 7)) * 8;
  const int NT = NSEG * 32;

  {
    const ushort_t* Ab0 = A0 + (size_t)m0 * K;
    const ushort_t* Bb0 = B0 + (size_t)n0 * K;
#pragma unroll
    for (int t = 0; t < 2; ++t) {
      const ushort_t* Ab = Ab0 + t * 64;
      const ushort_t* Bb = Bb0 + t * 64;
      stage_chunk(Ab, K, 0,   &As_[t][0], tid);
      stage_chunk(Ab, K, 64,  &As_[t][0], tid);
      stage_chunk(Ab, K, 128, &As_[t][0], tid);
      stage_chunk(Ab, K, 192, &As_[t][0], tid);
      stage_chunk(Bb, K, 0,   &Bs_[t][0], tid);
      stage_chunk(Bb, K, 64,  &Bs_[t][0], tid);
    }
  }
  asm volatile("s_waitcnt vmcnt(6)" ::: "memory");
  __builtin_amdgcn_s_barrier();
  asm volatile("" ::: "memory");

  f32x4 acc[4][4] = {};
  int cur = 0;
  for (int kt = 0; kt < NT; ++kt) {
    const int st = kt + 2;
    const bool doStage = (st < NT);
    int sbuf = cur + 2; if (sbuf >= 3) sbuf -= 3;
    ushort_t* At  = &As_[cur][0];
    ushort_t* Bt  = &Bs_[cur][0];
    ushort_t* Ads = &As_[sbuf][0];
    ushort_t* Bds = &Bs_[sbuf][0];
    const ushort_t* Asb = A0;
    const ushort_t* Bsb = B0;
    if (doStage) {
      const int sg = st >> 5;
      const ushort_t* Ag = A0;
      const ushort_t* Bg = B0;
      if (NSEG >= 2 && sg == 1) Ag = A1;
      if (NSEG == 3 && sg == 2) { Ag = A2; Bg = B2; }
      Asb = Ag + (size_t)m0 * K + (size_t)(st & 31) * 64;
      Bsb = Bg + (size_t)n0 * K + (size_t)(st & 31) * 64;
    }
    s16x8 bf[4][2];
#pragma unroll
    for (int p = 0; p < 2; ++p) {
      s16x8 af[2][2];
#pragma unroll
      for (int i = 0; i < 2; ++i)
#pragma unroll
        for (int s = 0; s < 2; ++s)
          af[i][s] = *(const s16x8*)(At + aRowB + (p * 2 + i) * 1024 + ks8[s]);
      if (p == 0) {
#pragma unroll
        for (int nt = 0; nt < 4; ++nt)
#pragma unroll
          for (int s = 0; s < 2; ++s)
            bf[nt][s] = *(const s16x8*)(Bt + bRowB + nt * 1024 + ks8[s]);
      }
      if (doStage) {
        if (p == 0) {
          stage_chunk(Asb, K, 0,   Ads, tid);
          stage_chunk(Asb, K, 64,  Ads, tid);
          stage_chunk(Asb, K, 128, Ads, tid);
        } else {
          stage_chunk(Asb, K, 192, Ads, tid);
          stage_chunk(Bsb, K, 0,   Bds, tid);
          stage_chunk(Bsb, K, 64,  Bds, tid);
        }
      }
      asm volatile("s_waitcnt lgkmcnt(0)" ::: "memory");
      __builtin_amdgcn_sched_barrier(0);
      __builtin_amdgcn_s_setprio(1);
#pragma unroll
      for (int i = 0; i < 2; ++i)
#pragma unroll
        for (int nt = 0; nt < 4; ++nt)
#pragma unroll
          for (int s = 0; s < 2; ++s)
            acc[p * 2 + i][nt] = mfma_bf16(af[i][s], bf[nt][s], acc[p * 2 + i][nt]);
      __builtin_amdgcn_s_setprio(0);
      if (p == 1) {
        if (doStage) asm volatile("s_waitcnt vmcnt(6)" ::: "memory");
        else         asm volatile("s_waitcnt vmcnt(0)" ::: "memory");
        __builtin_amdgcn_s_barrier();
        asm volatile("" ::: "memory");
      }
    }
    cur = (cur == 2) ? 0 : cur + 1;
  }

#pragma unroll
  for (int mt = 0; mt < 4; ++mt)
#pragma unroll
    for (int nt = 0; nt < 4; ++nt)
#pragma unroll
      for (int r = 0; r < 4; ++r) {
        int row = m0 + wrM + mt * 16 + quad * 4 + r;
        int col = n0 + wcN + nt * 16 + l16;
        float v = acc[mt][nt][r];
        if (OUT == 2) {
          Cf[(size_t)row * N + col] = v + bias[col];
        } else if (OUT == 1) {
          unsigned short h = f2b(v);
          Co[(size_t)row * N + col]  = h;
          Col[(size_t)row * N + col] = f2b(v - b2f(h));
        } else {
          Co[(size_t)row * N + col] = f2b(v);
        }
      }
}

// ---------------- MFMA flash attention, 64-query tile per block ----------------
__global__ __launch_bounds__(256) void k_fattn(const ushort_t* __restrict__ Qh,
                                               const ushort_t* __restrict__ Ql,
                                               const ushort_t* __restrict__ Kh,
                                               const ushort_t* __restrict__ Vt,
                                               const int* __restrict__ amask,
                                               ushort_t* __restrict__ AO) {
  __shared__ ushort_t Ksh[64][136];
  __shared__ ushort_t Vs[128][72];
  __shared__ ushort_t ps[4][16][72];
  __shared__ int ams[320];
  const int tid = threadIdx.x;
  const int wave = tid >> 6, lane = tid & 63;
  const int quad = lane >> 4, l16 = lane & 15;
  const int qt = blockIdx.x, h = blockIdx.y, b = blockIdx.z;
  const int q0 = qt * 64;

  for (int x = tid; x < 320; x += 256) {
    int j = q0 - 256 + x;
    ams[x] = (j >= 0) ? amask[b * S_ + j] : 0;
  }

  const int qrowA = q0 + wave * 16 + l16;
  const ushort_t* qbh = Qh + ((size_t)(b * S_ + qrowA) * D_) + h * HD_;
  const ushort_t* qbl = Ql + ((size_t)(b * S_ + qrowA) * D_) + h * HD_;
  s16x8 qh[4], ql[4];
#pragma unroll
  for (int kk = 0; kk < 4; kk++) {
    qh[kk] = *(const s16x8*)(qbh + kk * 32 + quad * 8);
    ql[kk] = *(const s16x8*)(qbl + kk * 32 + quad * 8);
  }

  f32x4 O[8] = {};
  float m_run[4], l_run[4];
#pragma unroll
  for (int r = 0; r < 4; r++) { m_run[r] = -3.0e38f; l_run[r] = 0.f; }

  const int t0 = (qt < 4) ? (4 - qt) : 0;
  for (int t = t0; t < 5; t++) {
    const int kb = q0 - 256 + 64 * t;
    __syncthreads();
    {
      const int key = tid >> 2, dimb = (tid & 3) * 32;
      const ushort_t* kgh = Kh + ((size_t)(b * S_ + kb + key) * D_) + h * HD_ + dimb;
#pragma unroll
      for (int u = 0; u < 4; u++)
        *(uint4*)&Ksh[key][dimb + u * 8] = *(const uint4*)(kgh + u * 8);
      const int hd = tid >> 1, keyb = (tid & 1) * 32;
      const ushort_t* vg = Vt + ((size_t)(b * D_ + h * HD_ + hd) * S_) + kb + keyb;
#pragma unroll
      for (int u = 0; u < 4; u++)
        *(uint4*)&Vs[hd][keyb + u * 8] = *(const uint4*)(vg + u * 8);
    }
    __syncthreads();

    f32x4 sacc[4] = {};
#pragma unroll
    for (int kk = 0; kk < 4; kk++)
#pragma unroll
      for (int nt = 0; nt < 4; nt++) {
        s16x8 kfh = *(const s16x8*)&Ksh[nt * 16 + l16][kk * 32 + quad * 8];
        sacc[nt] = mfma_bf16(qh[kk], kfh, sacc[nt]);
        sacc[nt] = mfma_bf16(ql[kk], kfh, sacc[nt]);
      }

#pragma unroll
    for (int nt = 0; nt < 4; nt++) {
      const int j = kb + nt * 16 + l16;
      const bool amok = ams[64 * t + nt * 16 + l16] != 0;
#pragma unroll
      for (int r = 0; r < 4; r++) {
        const int iq = q0 + wave * 16 + quad * 4 + r;
        const bool ok = amok && (j <= iq) && (j > iq - WIN_);
        if (!ok) sacc[nt][r] = -3.0e38f;
      }
    }
    float mt[4];
#pragma unroll
    for (int r = 0; r < 4; r++) {
      mt[r] = fmaxf(fmaxf(sacc[0][r], sacc[1][r]), fmaxf(sacc[2][r], sacc[3][r]));
      mt[r] = fmaxf(mt[r], __shfl_xor(mt[r], 1));
      mt[r] = fmaxf(mt[r], __shfl_xor(mt[r], 2));
      mt[r] = fmaxf(mt[r], __shfl_xor(mt[r], 4));
      mt[r] = fmaxf(mt[r], __shfl_xor(mt[r], 8));
    }
    float alpha[4], lt[4];
#pragma unroll
    for (int r = 0; r < 4; r++) {
      float mnew = fmaxf(m_run[r], mt[r]);
      alpha[r] = __expf(m_run[r] - mnew);
      m_run[r] = mnew;
      lt[r] = 0.f;
#pragma unroll
      for (int nt = 0; nt < 4; nt++) {
        float s = sacc[nt][r];
        float p = (s > -1.0e30f) ? __expf(s - mnew) : 0.f;
        sacc[nt][r] = p;
        lt[r] += p;
      }
      lt[r] += __shfl_xor(lt[r], 1);
      lt[r] += __shfl_xor(lt[r], 2);
      lt[r] += __shfl_xor(lt[r], 4);
      lt[r] += __shfl_xor(lt[r], 8);
      l_run[r] = l_run[r] * alpha[r] + lt[r];
    }
#pragma unroll
    for (int o = 0; o < 8; o++)
#pragma unroll
      for (int r = 0; r < 4; r++) O[o][r] *= alpha[r];
#pragma unroll
    for (int nt = 0; nt < 4; nt++)
#pragma unroll
      for (int r = 0; r < 4; r++)
        ps[wave][quad * 4 + r][nt * 16 + l16] = f2b(sacc[nt][r]);
    __syncthreads();
#pragma unroll
    for (int kk2 = 0; kk2 < 2; kk2++) {
      s16x8 pf = *(const s16x8*)&ps[wave][l16][kk2 * 32 + quad * 8];
#pragma unroll
      for (int o = 0; o < 8; o++) {
        s16x8 vf = *(const s16x8*)&Vs[o * 16 + l16][kk2 * 32 + quad * 8];
        O[o] = mfma_bf16(pf, vf, O[o]);
      }
    }
  }
#pragma unroll
  for (int r = 0; r < 4; r++) l_run[r] = 1.0f / l_run[r];
#pragma unroll
  for (int o = 0; o < 8; o++)
#pragma unroll
    for (int r = 0; r < 4; r++) {
      int row = q0 + wave * 16 + quad * 4 + r;
      AO[((size_t)(b * S_ + row) * D_) + h * HD_ + o * 16 + l16] = f2b(O[o][r] * l_run[r]);
    }
}

extern "C" void kernel_launch(void* const* d_in, const int* in_sizes, int n_in,
                              void* d_out, int out_size, void* d_ws, size_t ws_size,
                              hipStream_t stream) {
  const float* hs    = (const float*)d_in[0];
  const int*   amask = (const int*)d_in[1];
  const float* Wq    = (const float*)d_in[2];
  const float* Wk    = (const float*)d_in[3];
  const float* Wv    = (const float*)d_in[4];
  const float* Wo    = (const float*)d_in[5];
  const float* bo    = (const float*)d_in[6];
  float* out = (float*)d_out;

  char* p = (char*)d_ws;
  ushort_t* hsHi = (ushort_t*)p; p += (size_t)16 << 20;
  ushort_t* hsLo = (ushort_t*)p; p += (size_t)16 << 20;
  ushort_t* WqTh = (ushort_t*)p; p += (size_t)8 << 20;
  ushort_t* WqTl = (ushort_t*)p; p += (size_t)8 << 20;
  ushort_t* WkTh = (ushort_t*)p; p += (size_t)8 << 20;
  ushort_t* WkTl = (ushort_t*)p; p += (size_t)8 << 20;  (void)WkTl;
  ushort_t* WvTh = (ushort_t*)p; p += (size_t)8 << 20;
  ushort_t* WoTh = (ushort_t*)p; p += (size_t)8 << 20;
  ushort_t* Qhb  = (ushort_t*)p; p += (size_t)16 << 20;
  ushort_t* Qlb  = (ushort_t*)p; p += (size_t)16 << 20;
  ushort_t* Khb  = (ushort_t*)p; p += (size_t)16 << 20;
  ushort_t* Vb   = (ushort_t*)p; p += (size_t)16 << 20;
  ushort_t* Vt   = (ushort_t*)p; p += (size_t)16 << 20;

  k_split<<<M_ * D_ / 1024, 256, 0, stream>>>(hs, hsHi, hsLo, M_ * D_);
  dim3 tb(32, 8), tg4(D_ / 32, D_ / 32, 4);
  k_transpose4<<<tg4, tb, 0, stream>>>(Wq, Wk, Wv, Wo, WqTh, WqTl, WkTh, nullptr, WvTh, WoTh);

  // fused QKV: grid (24,16) = 384 blocks; bx<8 Q (3 segs), <16 K (2), else V (1)
  dim3 gq(24, 16);
  k_qkv<<<gq, 512, 0, stream>>>(hsHi, hsLo, WqTh, WqTl, WkTh, WvTh, Qhb, Qlb, Khb, Vb);

  dim3 vg(D_ / 32, S_ / 32, B_);
  k_vtrans<<<vg, tb, 0, stream>>>(Vb, Vt);

  dim3 ag(S_ / 64, H_, B_);  // (32, 16, 2)
  k_fattn<<<ag, 256, 0, stream>>>(Qhb, Qlb, Khb, Vt, amask, hsHi /*AO*/);

  // O: plain, f32 + bias epilogue (256x128 tile)
  dim3 gg(D_ / 128, M_ / 256);
  k_gemm8<1, 2><<<gg, 512, 0, stream>>>(hsHi /*AO*/, nullptr, nullptr, WoTh, nullptr,
                                        nullptr, nullptr, out, bo, M_, D_, D_);
}